// Round 1
// baseline (1563.796 us; speedup 1.0000x reference)
//
#include <hip/hip_runtime.h>

// ---------------------------------------------------------------------------
// GPT-J attention on MI355X (gfx950), bf16 MFMA pipeline.
// B=2 S=2048 E=4096 H=16 D=256 ROT=64
// ---------------------------------------------------------------------------

typedef __bf16 bf16;
typedef bf16  bf16x4 __attribute__((ext_vector_type(4)));
typedef bf16  bf16x8 __attribute__((ext_vector_type(8)));
typedef float f32x4  __attribute__((ext_vector_type(4)));

#define SEQ 2048
#define ED  4096
#define NH  16
#define HD  256

__device__ __forceinline__ void async_load16(const void* g, void* l) {
  __builtin_amdgcn_global_load_lds(
      (const __attribute__((address_space(1))) void*)g,
      (__attribute__((address_space(3))) void*)l, 16, 0, 0);
}

// ---------------------------------------------------------------------------
// fp32 -> bf16 conversion, 4 elems/thread
// ---------------------------------------------------------------------------
__global__ void cvt_f32_bf16(const float* __restrict__ src,
                             bf16* __restrict__ dst, int n) {
  int idx = (blockIdx.x * 256 + threadIdx.x) * 4;
  if (idx < n) {
    float4 v = *(const float4*)(src + idx);
    bf16x4 o;
    o.x = (bf16)v.x; o.y = (bf16)v.y; o.z = (bf16)v.z; o.w = (bf16)v.w;
    *(bf16x4*)(dst + idx) = o;
  }
}

// ---------------------------------------------------------------------------
// bt-GEMM: C[m,n] = dot(A[m,:], W[n,:]), A: 4096xK bf16, W: (3*4096)xK bf16.
// 128x128 tile, 4 waves, BK=32, global_load_lds staging (16B).
// Epilogue scatters Q,K -> (b,h,s,d) and V -> (b,h,d,s), all bf16.
// ---------------------------------------------------------------------------
__global__ __launch_bounds__(256) void gemm_qkv(
    const bf16* __restrict__ A, const bf16* __restrict__ W,
    bf16* __restrict__ Qb, bf16* __restrict__ Kb, bf16* __restrict__ Vb) {
  __shared__ bf16 As[128 * 32];
  __shared__ bf16 Bs[128 * 32];
  const int tid = threadIdx.x;
  const int w = tid >> 6, lane = tid & 63;
  const int wm = w >> 1, wn = w & 1;
  const int lo = lane & 15, hi = lane >> 4;
  const int tm = blockIdx.x * 128;
  const int tn = blockIdx.y * 128;  // 0..12287

  const int rA0 = lane >> 2;          // row-within-chunk
  const int cA0 = (lane & 3) * 8;     // k offset

  const bf16* Ab = A + (size_t)tm * ED;
  const bf16* Wb = W + (size_t)tn * ED;

  f32x4 acc[4][4] = {};

  for (int k0 = 0; k0 < ED; k0 += 32) {
#pragma unroll
    for (int i = 0; i < 2; ++i) {
      int ci = w * 2 + i;
      int r = ci * 16 + rA0;
      async_load16(Ab + (size_t)r * ED + k0 + cA0, &As[ci * 512]);
      async_load16(Wb + (size_t)r * ED + k0 + cA0, &Bs[ci * 512]);
    }
    __syncthreads();
    bf16x8 af[4], bfr[4];
#pragma unroll
    for (int mt = 0; mt < 4; ++mt)
      af[mt] = *(const bf16x8*)&As[(wm * 64 + mt * 16 + lo) * 32 + hi * 8];
#pragma unroll
    for (int nt = 0; nt < 4; ++nt)
      bfr[nt] = *(const bf16x8*)&Bs[(wn * 64 + nt * 16 + lo) * 32 + hi * 8];
#pragma unroll
    for (int mt = 0; mt < 4; ++mt)
#pragma unroll
      for (int nt = 0; nt < 4; ++nt)
        acc[mt][nt] = __builtin_amdgcn_mfma_f32_16x16x32_bf16(
            af[mt], bfr[nt], acc[mt][nt], 0, 0, 0);
    __syncthreads();
  }

  const int widx = tn >> 12;     // 0=Q 1=K 2=V
  const int f0 = tn & 4095;
#pragma unroll
  for (int mt = 0; mt < 4; ++mt) {
#pragma unroll
    for (int nt = 0; nt < 4; ++nt) {
#pragma unroll
      for (int r = 0; r < 4; ++r) {
        int m = tm + wm * 64 + mt * 16 + hi * 4 + r;
        int f = f0 + wn * 64 + nt * 16 + lo;
        int b = m >> 11, s = m & 2047;
        int h = f >> 8, d = f & 255;
        bf16 bv = (bf16)acc[mt][nt][r];
        if (widx == 0)
          Qb[(((size_t)(b * NH + h) * SEQ) + s) * HD + d] = bv;
        else if (widx == 1)
          Kb[(((size_t)(b * NH + h) * SEQ) + s) * HD + d] = bv;
        else
          Vb[(((size_t)(b * NH + h) * HD) + d) * SEQ + s] = bv;
      }
    }
  }
}

// ---------------------------------------------------------------------------
// same GEMM, fp32 epilogue to d_out (row-major 4096x4096)
// ---------------------------------------------------------------------------
__global__ __launch_bounds__(256) void gemm_out(
    const bf16* __restrict__ A, const bf16* __restrict__ W,
    float* __restrict__ C) {
  __shared__ bf16 As[128 * 32];
  __shared__ bf16 Bs[128 * 32];
  const int tid = threadIdx.x;
  const int w = tid >> 6, lane = tid & 63;
  const int wm = w >> 1, wn = w & 1;
  const int lo = lane & 15, hi = lane >> 4;
  const int tm = blockIdx.x * 128;
  const int tn = blockIdx.y * 128;

  const int rA0 = lane >> 2;
  const int cA0 = (lane & 3) * 8;

  const bf16* Ab = A + (size_t)tm * ED;
  const bf16* Wb = W + (size_t)tn * ED;

  f32x4 acc[4][4] = {};

  for (int k0 = 0; k0 < ED; k0 += 32) {
#pragma unroll
    for (int i = 0; i < 2; ++i) {
      int ci = w * 2 + i;
      int r = ci * 16 + rA0;
      async_load16(Ab + (size_t)r * ED + k0 + cA0, &As[ci * 512]);
      async_load16(Wb + (size_t)r * ED + k0 + cA0, &Bs[ci * 512]);
    }
    __syncthreads();
    bf16x8 af[4], bfr[4];
#pragma unroll
    for (int mt = 0; mt < 4; ++mt)
      af[mt] = *(const bf16x8*)&As[(wm * 64 + mt * 16 + lo) * 32 + hi * 8];
#pragma unroll
    for (int nt = 0; nt < 4; ++nt)
      bfr[nt] = *(const bf16x8*)&Bs[(wn * 64 + nt * 16 + lo) * 32 + hi * 8];
#pragma unroll
    for (int mt = 0; mt < 4; ++mt)
#pragma unroll
      for (int nt = 0; nt < 4; ++nt)
        acc[mt][nt] = __builtin_amdgcn_mfma_f32_16x16x32_bf16(
            af[mt], bfr[nt], acc[mt][nt], 0, 0, 0);
    __syncthreads();
  }

#pragma unroll
  for (int mt = 0; mt < 4; ++mt)
#pragma unroll
    for (int nt = 0; nt < 4; ++nt)
#pragma unroll
      for (int r = 0; r < 4; ++r) {
        int m = tm + wm * 64 + mt * 16 + hi * 4 + r;
        int n = tn + wn * 64 + nt * 16 + lo;
        C[(size_t)m * ED + n] = acc[mt][nt][r];
      }
}

// ---------------------------------------------------------------------------
// RoPE (interleaved pairs, first 64 dims of each head), in place on Q and K.
// One thread per (tensor, b, h, s, pair). 2*2*16*2048*32 = 4194304 threads.
// ---------------------------------------------------------------------------
__global__ void rope_kernel(bf16* __restrict__ Qb, bf16* __restrict__ Kb,
                            const int* __restrict__ pos_ids,
                            const float* __restrict__ emb) {
  int idx = blockIdx.x * 256 + threadIdx.x;
  int i = idx & 31;
  int s = (idx >> 5) & 2047;
  int h = (idx >> 16) & 15;
  int b = (idx >> 20) & 1;
  int t = idx >> 21;
  bf16* T = t ? Kb : Qb;
  int pos = pos_ids[b * SEQ + s];
  float sn = emb[pos * 64 + i];
  float cs = emb[pos * 64 + 32 + i];
  size_t base = (((size_t)(b * NH + h) * SEQ) + s) * HD + 2 * i;
  float x0 = (float)T[base], x1 = (float)T[base + 1];
  T[base]     = (bf16)(x0 * cs - x1 * sn);
  T[base + 1] = (bf16)(x1 * cs + x0 * sn);
}

// ---------------------------------------------------------------------------
// Flash attention (causal). Grid: (qt=32, bh=32). Block: 256 = 4 waves.
// Q tile 64 rows (16 per wave, held in regs), K/V tiles 64 cols.
// Ks[64][256] (s-major), Vs[256][64] (d-major, from pre-transposed V).
// P transform C-layout -> A-layout through LDS (aliases head of Ks).
// Score scale 1/sqrt(256)=1/16 applied post-MFMA.
// ---------------------------------------------------------------------------
__global__ __launch_bounds__(256) void attn_kernel(
    const bf16* __restrict__ Qb, const bf16* __restrict__ Kb,
    const bf16* __restrict__ Vb, bf16* __restrict__ AO) {
  __shared__ bf16 Ks[64 * 256];   // 32 KB (first 8 KB reused as P scratch)
  __shared__ bf16 Vs[256 * 64];   // 32 KB
  const int tid = threadIdx.x;
  const int w = tid >> 6, lane = tid & 63;
  const int lo = lane & 15, hi = lane >> 4;
  const int qt = blockIdx.x;   // 0..31
  const int bh = blockIdx.y;   // 0..31

  const bf16* Qh = Qb + (size_t)bh * SEQ * HD;
  const bf16* Kh = Kb + (size_t)bh * SEQ * HD;
  const bf16* Vh = Vb + (size_t)bh * HD * SEQ;

  // Q fragments for this wave's 16-row strip (A-layout), 8 k-steps of 32
  bf16x8 aq[8];
  const int qrow = qt * 64 + w * 16 + lo;
#pragma unroll
  for (int ks = 0; ks < 8; ++ks)
    aq[ks] = *(const bf16x8*)(Qh + (size_t)qrow * HD + ks * 32 + hi * 8);

  f32x4 o[16] = {};
  float mrow[4], lrow[4];
#pragma unroll
  for (int r = 0; r < 4; ++r) { mrow[r] = -3e38f; lrow[r] = 0.f; }

  for (int kt = 0; kt <= qt; ++kt) {
    // stage K tile: rows kt*64..+63, 256 d each (512 B/row)
#pragma unroll
    for (int i = 0; i < 8; ++i) {
      int ci = w * 8 + i;
      int r = ci * 2 + (lane >> 5);
      int dc = (lane & 31) * 8;
      async_load16(Kh + ((size_t)(kt * 64 + r)) * HD + dc, &Ks[ci * 512]);
    }
    // stage V tile (transposed source): d rows 0..255, s cols kt*64..+63
#pragma unroll
    for (int i = 0; i < 8; ++i) {
      int ci = w * 8 + i;
      int d = ci * 8 + (lane >> 3);
      int sc = (lane & 7) * 8;
      async_load16(Vh + (size_t)d * SEQ + kt * 64 + sc, &Vs[ci * 512]);
    }
    __syncthreads();

    // S strip: 16 rows x 64 cols
    float sv[4][4];
#pragma unroll
    for (int nt = 0; nt < 4; ++nt) {
      f32x4 sacc = {};
#pragma unroll
      for (int ks = 0; ks < 8; ++ks) {
        bf16x8 bk = *(const bf16x8*)&Ks[(nt * 16 + lo) * HD + ks * 32 + hi * 8];
        sacc = __builtin_amdgcn_mfma_f32_16x16x32_bf16(aq[ks], bk, sacc, 0, 0, 0);
      }
#pragma unroll
      for (int r = 0; r < 4; ++r) {
        float x = sacc[r] * 0.0625f;
        if (kt == qt) {
          int col = kt * 64 + nt * 16 + lo;
          int row = qt * 64 + w * 16 + hi * 4 + r;
          if (col > row) x = -1e30f;
        }
        sv[nt][r] = x;
      }
    }

    // online softmax over the 64 new cols (row lives in 16 lanes sharing hi)
    float alpha[4];
#pragma unroll
    for (int r = 0; r < 4; ++r) {
      float mx = fmaxf(fmaxf(sv[0][r], sv[1][r]), fmaxf(sv[2][r], sv[3][r]));
      mx = fmaxf(mx, __shfl_xor(mx, 1));
      mx = fmaxf(mx, __shfl_xor(mx, 2));
      mx = fmaxf(mx, __shfl_xor(mx, 4));
      mx = fmaxf(mx, __shfl_xor(mx, 8));
      float mnew = fmaxf(mrow[r], mx);
      alpha[r] = __expf(mrow[r] - mnew);
      mrow[r] = mnew;
      float sum = 0.f;
#pragma unroll
      for (int nt = 0; nt < 4; ++nt) {
        float p = __expf(sv[nt][r] - mnew);
        sv[nt][r] = p;
        sum += p;
      }
      sum += __shfl_xor(sum, 1);
      sum += __shfl_xor(sum, 2);
      sum += __shfl_xor(sum, 4);
      sum += __shfl_xor(sum, 8);
      lrow[r] = lrow[r] * alpha[r] + sum;
    }

    // rescale O by alpha (same row mapping as S)
#pragma unroll
    for (int nt2 = 0; nt2 < 16; ++nt2)
#pragma unroll
      for (int r = 0; r < 4; ++r) o[nt2][r] *= alpha[r];

    // P: C-layout -> LDS (wave-private 16x64 strip in head of Ks) -> A-layout
    __syncthreads();  // all Ks reads done before overwrite
#pragma unroll
    for (int nt = 0; nt < 4; ++nt)
#pragma unroll
      for (int r = 0; r < 4; ++r)
        Ks[w * 1024 + (hi * 4 + r) * 64 + nt * 16 + lo] = (bf16)sv[nt][r];
    __syncthreads();
    bf16x8 pa[2];
#pragma unroll
    for (int k2 = 0; k2 < 2; ++k2)
      pa[k2] = *(const bf16x8*)&Ks[w * 1024 + lo * 64 + k2 * 32 + hi * 8];

    // O += P @ V  (16x64 @ 64x256)
#pragma unroll
    for (int nt2 = 0; nt2 < 16; ++nt2) {
#pragma unroll
      for (int k2 = 0; k2 < 2; ++k2) {
        bf16x8 bv = *(const bf16x8*)&Vs[(nt2 * 16 + lo) * 64 + k2 * 32 + hi * 8];
        o[nt2] = __builtin_amdgcn_mfma_f32_16x16x32_bf16(pa[k2], bv, o[nt2], 0, 0, 0);
      }
    }
    __syncthreads();  // Vs/P reads done before next staging
  }

  // epilogue: normalize, write AO as (b, s, h*256+d) bf16
  const int b = bh >> 4, h = bh & 15;
#pragma unroll
  for (int r = 0; r < 4; ++r) {
    float inv = 1.f / lrow[r];
    int srow = qt * 64 + w * 16 + hi * 4 + r;
    size_t base = ((size_t)(b * SEQ + srow)) * ED + h * HD;
#pragma unroll
    for (int nt2 = 0; nt2 < 16; ++nt2)
      AO[base + nt2 * 16 + lo] = (bf16)(o[nt2][r] * inv);
  }
}

// ---------------------------------------------------------------------------
// launch
// ---------------------------------------------------------------------------
extern "C" void kernel_launch(void* const* d_in, const int* in_sizes, int n_in,
                              void* d_out, int out_size, void* d_ws,
                              size_t ws_size, hipStream_t stream) {
  const float* hs  = (const float*)d_in[0];
  const int*   pos = (const int*)d_in[1];
  const float* qw  = (const float*)d_in[2];
  const float* kw  = (const float*)d_in[3];
  const float* vw  = (const float*)d_in[4];
  const float* ow  = (const float*)d_in[5];
  const float* emb = (const float*)d_in[6];
  float* out = (float*)d_out;

  char* ws = (char*)d_ws;
  const size_t MB = 1024 * 1024;
  // Hb [0,32MB) -- reused as AO after gemm_qkv consumes it
  // Wqkv [32MB,128MB) -- first 32MB reused as Wo after gemm_qkv
  // Qb [128,160) Kb [160,192) Vb [192,224)
  bf16* Hb   = (bf16*)(ws);
  bf16* AO   = (bf16*)(ws);
  bf16* Wqkv = (bf16*)(ws + 32 * MB);
  bf16* Wo   = (bf16*)(ws + 32 * MB);
  bf16* Qb   = (bf16*)(ws + 128 * MB);
  bf16* Kb   = (bf16*)(ws + 160 * MB);
  bf16* Vb   = (bf16*)(ws + 192 * MB);

  const int n = ED * ED;            // 16777216
  const int cvtg = n / 1024;        // 16384 blocks

  cvt_f32_bf16<<<cvtg, 256, 0, stream>>>(hs, Hb, n);
  cvt_f32_bf16<<<cvtg, 256, 0, stream>>>(qw, Wqkv, n);
  cvt_f32_bf16<<<cvtg, 256, 0, stream>>>(kw, Wqkv + (size_t)n, n);
  cvt_f32_bf16<<<cvtg, 256, 0, stream>>>(vw, Wqkv + 2 * (size_t)n, n);

  gemm_qkv<<<dim3(32, 96), 256, 0, stream>>>(Hb, Wqkv, Qb, Kb, Vb);

  // convert out_w AFTER gemm_qkv (aliases Wqkv head)
  cvt_f32_bf16<<<cvtg, 256, 0, stream>>>(ow, Wo, n);

  rope_kernel<<<16384, 256, 0, stream>>>(Qb, Kb, pos, emb);

  attn_kernel<<<dim3(32, 32), 256, 0, stream>>>(Qb, Kb, Vb, AO);

  gemm_out<<<dim3(32, 32), 256, 0, stream>>>(AO, Wo, out);
}

// Round 2
// 1347.138 us; speedup vs baseline: 1.1608x; 1.1608x over previous
//
#include <hip/hip_runtime.h>

// ---------------------------------------------------------------------------
// GPT-J attention on MI355X (gfx950), bf16 MFMA pipeline.
// B=2 S=2048 E=4096 H=16 D=256 ROT=64
// R2: XOR-swizzled attention LDS (kills 16-way bank conflicts),
//     wave-private P scratch (removes 2 barriers/iter).
// ---------------------------------------------------------------------------

typedef __bf16 bf16;
typedef bf16  bf16x4 __attribute__((ext_vector_type(4)));
typedef bf16  bf16x8 __attribute__((ext_vector_type(8)));
typedef float f32x4  __attribute__((ext_vector_type(4)));

#define SEQ 2048
#define ED  4096
#define NH  16
#define HD  256

__device__ __forceinline__ void async_load16(const void* g, void* l) {
  __builtin_amdgcn_global_load_lds(
      (const __attribute__((address_space(1))) void*)g,
      (__attribute__((address_space(3))) void*)l, 16, 0, 0);
}

// ---------------------------------------------------------------------------
// fp32 -> bf16 conversion, 4 elems/thread
// ---------------------------------------------------------------------------
__global__ void cvt_f32_bf16(const float* __restrict__ src,
                             bf16* __restrict__ dst, int n) {
  int idx = (blockIdx.x * 256 + threadIdx.x) * 4;
  if (idx < n) {
    float4 v = *(const float4*)(src + idx);
    bf16x4 o;
    o.x = (bf16)v.x; o.y = (bf16)v.y; o.z = (bf16)v.z; o.w = (bf16)v.w;
    *(bf16x4*)(dst + idx) = o;
  }
}

// ---------------------------------------------------------------------------
// bt-GEMM: C[m,n] = dot(A[m,:], W[n,:]), A: 4096xK bf16, W: (3*4096)xK bf16.
// 128x128 tile, 4 waves, BK=32, global_load_lds staging (16B).
// Epilogue scatters Q,K -> (b,h,s,d) and V -> (b,h,d,s), all bf16.
// ---------------------------------------------------------------------------
__global__ __launch_bounds__(256) void gemm_qkv(
    const bf16* __restrict__ A, const bf16* __restrict__ W,
    bf16* __restrict__ Qb, bf16* __restrict__ Kb, bf16* __restrict__ Vb) {
  __shared__ bf16 As[128 * 32];
  __shared__ bf16 Bs[128 * 32];
  const int tid = threadIdx.x;
  const int w = tid >> 6, lane = tid & 63;
  const int wm = w >> 1, wn = w & 1;
  const int lo = lane & 15, hi = lane >> 4;
  const int tm = blockIdx.x * 128;
  const int tn = blockIdx.y * 128;  // 0..12287

  const int rA0 = lane >> 2;          // row-within-chunk
  const int cA0 = (lane & 3) * 8;     // k offset

  const bf16* Ab = A + (size_t)tm * ED;
  const bf16* Wb = W + (size_t)tn * ED;

  f32x4 acc[4][4] = {};

  for (int k0 = 0; k0 < ED; k0 += 32) {
#pragma unroll
    for (int i = 0; i < 2; ++i) {
      int ci = w * 2 + i;
      int r = ci * 16 + rA0;
      async_load16(Ab + (size_t)r * ED + k0 + cA0, &As[ci * 512]);
      async_load16(Wb + (size_t)r * ED + k0 + cA0, &Bs[ci * 512]);
    }
    __syncthreads();
    bf16x8 af[4], bfr[4];
#pragma unroll
    for (int mt = 0; mt < 4; ++mt)
      af[mt] = *(const bf16x8*)&As[(wm * 64 + mt * 16 + lo) * 32 + hi * 8];
#pragma unroll
    for (int nt = 0; nt < 4; ++nt)
      bfr[nt] = *(const bf16x8*)&Bs[(wn * 64 + nt * 16 + lo) * 32 + hi * 8];
#pragma unroll
    for (int mt = 0; mt < 4; ++mt)
#pragma unroll
      for (int nt = 0; nt < 4; ++nt)
        acc[mt][nt] = __builtin_amdgcn_mfma_f32_16x16x32_bf16(
            af[mt], bfr[nt], acc[mt][nt], 0, 0, 0);
    __syncthreads();
  }

  const int widx = tn >> 12;     // 0=Q 1=K 2=V
  const int f0 = tn & 4095;
#pragma unroll
  for (int mt = 0; mt < 4; ++mt) {
#pragma unroll
    for (int nt = 0; nt < 4; ++nt) {
#pragma unroll
      for (int r = 0; r < 4; ++r) {
        int m = tm + wm * 64 + mt * 16 + hi * 4 + r;
        int f = f0 + wn * 64 + nt * 16 + lo;
        int b = m >> 11, s = m & 2047;
        int h = f >> 8, d = f & 255;
        bf16 bv = (bf16)acc[mt][nt][r];
        if (widx == 0)
          Qb[(((size_t)(b * NH + h) * SEQ) + s) * HD + d] = bv;
        else if (widx == 1)
          Kb[(((size_t)(b * NH + h) * SEQ) + s) * HD + d] = bv;
        else
          Vb[(((size_t)(b * NH + h) * HD) + d) * SEQ + s] = bv;
      }
    }
  }
}

// ---------------------------------------------------------------------------
// same GEMM, fp32 epilogue to d_out (row-major 4096x4096)
// ---------------------------------------------------------------------------
__global__ __launch_bounds__(256) void gemm_out(
    const bf16* __restrict__ A, const bf16* __restrict__ W,
    float* __restrict__ C) {
  __shared__ bf16 As[128 * 32];
  __shared__ bf16 Bs[128 * 32];
  const int tid = threadIdx.x;
  const int w = tid >> 6, lane = tid & 63;
  const int wm = w >> 1, wn = w & 1;
  const int lo = lane & 15, hi = lane >> 4;
  const int tm = blockIdx.x * 128;
  const int tn = blockIdx.y * 128;

  const int rA0 = lane >> 2;
  const int cA0 = (lane & 3) * 8;

  const bf16* Ab = A + (size_t)tm * ED;
  const bf16* Wb = W + (size_t)tn * ED;

  f32x4 acc[4][4] = {};

  for (int k0 = 0; k0 < ED; k0 += 32) {
#pragma unroll
    for (int i = 0; i < 2; ++i) {
      int ci = w * 2 + i;
      int r = ci * 16 + rA0;
      async_load16(Ab + (size_t)r * ED + k0 + cA0, &As[ci * 512]);
      async_load16(Wb + (size_t)r * ED + k0 + cA0, &Bs[ci * 512]);
    }
    __syncthreads();
    bf16x8 af[4], bfr[4];
#pragma unroll
    for (int mt = 0; mt < 4; ++mt)
      af[mt] = *(const bf16x8*)&As[(wm * 64 + mt * 16 + lo) * 32 + hi * 8];
#pragma unroll
    for (int nt = 0; nt < 4; ++nt)
      bfr[nt] = *(const bf16x8*)&Bs[(wn * 64 + nt * 16 + lo) * 32 + hi * 8];
#pragma unroll
    for (int mt = 0; mt < 4; ++mt)
#pragma unroll
      for (int nt = 0; nt < 4; ++nt)
        acc[mt][nt] = __builtin_amdgcn_mfma_f32_16x16x32_bf16(
            af[mt], bfr[nt], acc[mt][nt], 0, 0, 0);
    __syncthreads();
  }

#pragma unroll
  for (int mt = 0; mt < 4; ++mt)
#pragma unroll
    for (int nt = 0; nt < 4; ++nt)
#pragma unroll
      for (int r = 0; r < 4; ++r) {
        int m = tm + wm * 64 + mt * 16 + hi * 4 + r;
        int n = tn + wn * 64 + nt * 16 + lo;
        C[(size_t)m * ED + n] = acc[mt][nt][r];
      }
}

// ---------------------------------------------------------------------------
// RoPE (interleaved pairs, first 64 dims of each head), in place on Q and K.
// ---------------------------------------------------------------------------
__global__ void rope_kernel(bf16* __restrict__ Qb, bf16* __restrict__ Kb,
                            const int* __restrict__ pos_ids,
                            const float* __restrict__ emb) {
  int idx = blockIdx.x * 256 + threadIdx.x;
  int i = idx & 31;
  int s = (idx >> 5) & 2047;
  int h = (idx >> 16) & 15;
  int b = (idx >> 20) & 1;
  int t = idx >> 21;
  bf16* T = t ? Kb : Qb;
  int pos = pos_ids[b * SEQ + s];
  float sn = emb[pos * 64 + i];
  float cs = emb[pos * 64 + 32 + i];
  size_t base = (((size_t)(b * NH + h) * SEQ) + s) * HD + 2 * i;
  float x0 = (float)T[base], x1 = (float)T[base + 1];
  T[base]     = (bf16)(x0 * cs - x1 * sn);
  T[base + 1] = (bf16)(x1 * cs + x0 * sn);
}

// ---------------------------------------------------------------------------
// Flash attention (causal). Grid: (qt=32, bh=32). Block: 256 = 4 waves.
// XOR-swizzled LDS: phys 16B-chunk = logical chunk ^ (row & 7).
//   Ks: 64 rows x 512 B (32 chunks/row)   -> 2-way max on b128 reads
//   Vs: 256 rows x 128 B (8 chunks/row)   -> 2-way max
//   Ps: per-wave 16 rows x 128 B          -> 2-way max, wave-private (no barrier)
// Swizzle inverted on the global-fetch side of global_load_lds
// (LDS addr is pinned to base + lane*16; we permute which global chunk
//  each lane fetches instead -- same cache lines, coalescing unchanged).
// ---------------------------------------------------------------------------
__global__ __launch_bounds__(256) void attn_kernel(
    const bf16* __restrict__ Qb, const bf16* __restrict__ Kb,
    const bf16* __restrict__ Vb, bf16* __restrict__ AO) {
  __shared__ bf16 Ks[64 * 256];    // 32 KB
  __shared__ bf16 Vs[256 * 64];    // 32 KB
  __shared__ bf16 Ps[4 * 16 * 64]; // 8 KB, wave-private strips
  const int tid = threadIdx.x;
  const int w = tid >> 6, lane = tid & 63;
  const int lo = lane & 15, hi = lane >> 4;
  const int qt = blockIdx.x;   // 0..31
  const int bh = blockIdx.y;   // 0..31

  const bf16* Qh = Qb + (size_t)bh * SEQ * HD;
  const bf16* Kh = Kb + (size_t)bh * SEQ * HD;
  const bf16* Vh = Vb + (size_t)bh * HD * SEQ;

  // Q fragments for this wave's 16-row strip (A-layout), 8 k-steps of 32
  bf16x8 aq[8];
  const int qrow = qt * 64 + w * 16 + lo;
#pragma unroll
  for (int ks = 0; ks < 8; ++ks)
    aq[ks] = *(const bf16x8*)(Qh + (size_t)qrow * HD + ks * 32 + hi * 8);

  f32x4 o[16] = {};
  float mrow[4], lrow[4];
#pragma unroll
  for (int r = 0; r < 4; ++r) { mrow[r] = -3e38f; lrow[r] = 0.f; }

  for (int kt = 0; kt <= qt; ++kt) {
    // stage K tile: 64 rows x 512 B; region ci covers 2 rows.
    // lane lands at phys chunk (lane&31); fetch logical chunk ^ (row&7).
#pragma unroll
    for (int i = 0; i < 8; ++i) {
      int ci = w * 8 + i;
      int r = ci * 2 + (lane >> 5);
      int cc = (lane & 31) ^ (r & 7);
      async_load16(Kh + ((size_t)(kt * 64 + r)) * HD + cc * 8, &Ks[ci * 512]);
    }
    // stage V tile: 256 d-rows x 128 B; region ci covers 8 rows.
#pragma unroll
    for (int i = 0; i < 8; ++i) {
      int ci = w * 8 + i;
      int d = ci * 8 + (lane >> 3);
      int cc = (lane & 7) ^ (d & 7);
      async_load16(Vh + (size_t)d * SEQ + kt * 64 + cc * 8, &Vs[ci * 512]);
    }
    __syncthreads();

    // S strip: 16 rows x 64 cols
    float sv[4][4];
#pragma unroll
    for (int nt = 0; nt < 4; ++nt) {
      f32x4 sacc = {};
#pragma unroll
      for (int ks = 0; ks < 8; ++ks) {
        int row = nt * 16 + lo;
        bf16x8 bk = *(const bf16x8*)
            &Ks[row * HD + ((((ks << 2) + hi) ^ (row & 7)) << 3)];
        sacc = __builtin_amdgcn_mfma_f32_16x16x32_bf16(aq[ks], bk, sacc, 0, 0, 0);
      }
#pragma unroll
      for (int r = 0; r < 4; ++r) {
        float x = sacc[r] * 0.0625f;
        if (kt == qt) {
          int col = kt * 64 + nt * 16 + lo;
          int row = qt * 64 + w * 16 + hi * 4 + r;
          if (col > row) x = -1e30f;
        }
        sv[nt][r] = x;
      }
    }

    // online softmax over the 64 new cols (row lives in 16 lanes sharing hi)
    float alpha[4];
#pragma unroll
    for (int r = 0; r < 4; ++r) {
      float mx = fmaxf(fmaxf(sv[0][r], sv[1][r]), fmaxf(sv[2][r], sv[3][r]));
      mx = fmaxf(mx, __shfl_xor(mx, 1));
      mx = fmaxf(mx, __shfl_xor(mx, 2));
      mx = fmaxf(mx, __shfl_xor(mx, 4));
      mx = fmaxf(mx, __shfl_xor(mx, 8));
      float mnew = fmaxf(mrow[r], mx);
      alpha[r] = __expf(mrow[r] - mnew);
      mrow[r] = mnew;
      float sum = 0.f;
#pragma unroll
      for (int nt = 0; nt < 4; ++nt) {
        float p = __expf(sv[nt][r] - mnew);
        sv[nt][r] = p;
        sum += p;
      }
      sum += __shfl_xor(sum, 1);
      sum += __shfl_xor(sum, 2);
      sum += __shfl_xor(sum, 4);
      sum += __shfl_xor(sum, 8);
      lrow[r] = lrow[r] * alpha[r] + sum;
    }

    // rescale O by alpha (same row mapping as S)
#pragma unroll
    for (int nt2 = 0; nt2 < 16; ++nt2)
#pragma unroll
      for (int r = 0; r < 4; ++r) o[nt2][r] *= alpha[r];

    // P: C-layout -> wave-private LDS strip (swizzled) -> A-layout.
    // No barrier needed: only this wave touches Ps[w].
#pragma unroll
    for (int nt = 0; nt < 4; ++nt)
#pragma unroll
      for (int r = 0; r < 4; ++r) {
        int prow = hi * 4 + r;
        int chunk = nt * 2 + (lo >> 3);
        Ps[w * 1024 + prow * 64 + (((chunk ^ (prow & 7)) << 3) | (lo & 7))] =
            (bf16)sv[nt][r];
      }
    bf16x8 pa[2];
#pragma unroll
    for (int k2 = 0; k2 < 2; ++k2)
      pa[k2] = *(const bf16x8*)
          &Ps[w * 1024 + lo * 64 + ((((k2 << 2) + hi) ^ (lo & 7)) << 3)];

    // O += P @ V  (16x64 @ 64x256)
#pragma unroll
    for (int nt2 = 0; nt2 < 16; ++nt2) {
#pragma unroll
      for (int k2 = 0; k2 < 2; ++k2) {
        int row = nt2 * 16 + lo;
        bf16x8 bv = *(const bf16x8*)
            &Vs[row * 64 + ((((k2 << 2) + hi) ^ (row & 7)) << 3)];
        o[nt2] = __builtin_amdgcn_mfma_f32_16x16x32_bf16(pa[k2], bv, o[nt2], 0, 0, 0);
      }
    }
    __syncthreads();  // Ks/Vs reads done before next staging
  }

  // epilogue: normalize, write AO as (b, s, h*256+d) bf16
  const int b = bh >> 4, h = bh & 15;
#pragma unroll
  for (int r = 0; r < 4; ++r) {
    float inv = 1.f / lrow[r];
    int srow = qt * 64 + w * 16 + hi * 4 + r;
    size_t base = ((size_t)(b * SEQ + srow)) * ED + h * HD;
#pragma unroll
    for (int nt2 = 0; nt2 < 16; ++nt2)
      AO[base + nt2 * 16 + lo] = (bf16)(o[nt2][r] * inv);
  }
}

// ---------------------------------------------------------------------------
// launch
// ---------------------------------------------------------------------------
extern "C" void kernel_launch(void* const* d_in, const int* in_sizes, int n_in,
                              void* d_out, int out_size, void* d_ws,
                              size_t ws_size, hipStream_t stream) {
  const float* hs  = (const float*)d_in[0];
  const int*   pos = (const int*)d_in[1];
  const float* qw  = (const float*)d_in[2];
  const float* kw  = (const float*)d_in[3];
  const float* vw  = (const float*)d_in[4];
  const float* ow  = (const float*)d_in[5];
  const float* emb = (const float*)d_in[6];
  float* out = (float*)d_out;

  char* ws = (char*)d_ws;
  const size_t MB = 1024 * 1024;
  // Hb [0,32MB) -- reused as AO after gemm_qkv consumes it
  // Wqkv [32MB,128MB) -- first 32MB reused as Wo after gemm_qkv
  // Qb [128,160) Kb [160,192) Vb [192,224)
  bf16* Hb   = (bf16*)(ws);
  bf16* AO   = (bf16*)(ws);
  bf16* Wqkv = (bf16*)(ws + 32 * MB);
  bf16* Wo   = (bf16*)(ws + 32 * MB);
  bf16* Qb   = (bf16*)(ws + 128 * MB);
  bf16* Kb   = (bf16*)(ws + 160 * MB);
  bf16* Vb   = (bf16*)(ws + 192 * MB);

  const int n = ED * ED;            // 16777216
  const int cvtg = n / 1024;        // 16384 blocks

  cvt_f32_bf16<<<cvtg, 256, 0, stream>>>(hs, Hb, n);
  cvt_f32_bf16<<<cvtg, 256, 0, stream>>>(qw, Wqkv, n);
  cvt_f32_bf16<<<cvtg, 256, 0, stream>>>(kw, Wqkv + (size_t)n, n);
  cvt_f32_bf16<<<cvtg, 256, 0, stream>>>(vw, Wqkv + 2 * (size_t)n, n);

  gemm_qkv<<<dim3(32, 96), 256, 0, stream>>>(Hb, Wqkv, Qb, Kb, Vb);

  // convert out_w AFTER gemm_qkv (aliases Wqkv head)
  cvt_f32_bf16<<<cvtg, 256, 0, stream>>>(ow, Wo, n);

  rope_kernel<<<16384, 256, 0, stream>>>(Qb, Kb, pos, emb);

  attn_kernel<<<dim3(32, 32), 256, 0, stream>>>(Qb, Kb, Vb, AO);

  gemm_out<<<dim3(32, 32), 256, 0, stream>>>(AO, Wo, out);
}

// Round 3
// 1196.566 us; speedup vs baseline: 1.3069x; 1.1258x over previous
//
#include <hip/hip_runtime.h>

// ---------------------------------------------------------------------------
// GPT-J attention on MI355X (gfx950), bf16 MFMA pipeline.
// B=2 S=2048 E=4096 H=16 D=256 ROT=64
// R3: gemm_qkv band-swizzle (LLC) + coalesced V epilogue + separate V
//     transpose kernel; attn causal qt-pairing (perfect balance);
//     vectorized rope; fused weight conversions.
// ---------------------------------------------------------------------------

typedef __bf16 bf16;
typedef bf16  bf16x4 __attribute__((ext_vector_type(4)));
typedef bf16  bf16x8 __attribute__((ext_vector_type(8)));
typedef float f32x4  __attribute__((ext_vector_type(4)));

#define SEQ 2048
#define ED  4096
#define NH  16
#define HD  256

__device__ __forceinline__ void async_load16(const void* g, void* l) {
  __builtin_amdgcn_global_load_lds(
      (const __attribute__((address_space(1))) void*)g,
      (__attribute__((address_space(3))) void*)l, 16, 0, 0);
}

// ---------------------------------------------------------------------------
// fused fp32 -> bf16 conversion, 4 sources, 4 elems/thread
// ---------------------------------------------------------------------------
__global__ void cvt4_f32_bf16(const float* __restrict__ s0,
                              const float* __restrict__ s1,
                              const float* __restrict__ s2,
                              const float* __restrict__ s3,
                              bf16* __restrict__ d0, bf16* __restrict__ d1,
                              bf16* __restrict__ d2, bf16* __restrict__ d3) {
  int sec = blockIdx.x >> 14;              // 16384 blocks / section
  int idx = ((blockIdx.x & 16383) * 256 + threadIdx.x) * 4;
  const float* s = sec == 0 ? s0 : sec == 1 ? s1 : sec == 2 ? s2 : s3;
  bf16* d = sec == 0 ? d0 : sec == 1 ? d1 : sec == 2 ? d2 : d3;
  float4 v = *(const float4*)(s + idx);
  bf16x4 o;
  o.x = (bf16)v.x; o.y = (bf16)v.y; o.z = (bf16)v.z; o.w = (bf16)v.w;
  *(bf16x4*)(d + idx) = o;
}

__global__ void cvt_f32_bf16(const float* __restrict__ src,
                             bf16* __restrict__ dst, int n) {
  int idx = (blockIdx.x * 256 + threadIdx.x) * 4;
  if (idx < n) {
    float4 v = *(const float4*)(src + idx);
    bf16x4 o;
    o.x = (bf16)v.x; o.y = (bf16)v.y; o.z = (bf16)v.z; o.w = (bf16)v.w;
    *(bf16x4*)(dst + idx) = o;
  }
}

// ---------------------------------------------------------------------------
// bt-GEMM: C[m,n] = dot(A[m,:], W[n,:]), A: 4096xK bf16, W: (3*4096)xK bf16.
// 128x128 tile, 4 waves, BK=32, global_load_lds staging (16B).
// Band swizzle: 8 n-tiles per band -> concurrent blocks share A and W.
// Epilogue: uniform coalesced store to (b,h,s,d) for Q, K, and V(tmp).
// ---------------------------------------------------------------------------
__global__ __launch_bounds__(256) void gemm_qkv(
    const bf16* __restrict__ A, const bf16* __restrict__ W,
    bf16* __restrict__ Qb, bf16* __restrict__ Kb, bf16* __restrict__ Vtmp) {
  __shared__ bf16 As[128 * 32];
  __shared__ bf16 Bs[128 * 32];
  const int tid = threadIdx.x;
  const int w = tid >> 6, lane = tid & 63;
  const int wm = w >> 1, wn = w & 1;
  const int lo = lane & 15, hi = lane >> 4;

  // band swizzle: flat id -> (m-tile, n-tile) with 8 n per band
  const int flat = blockIdx.y * 32 + blockIdx.x;
  const int band = flat >> 8;                // 0..11
  const int xm = (flat & 255) >> 3;          // 0..31
  const int xn = (band << 3) | (flat & 7);   // 0..95
  const int tm = xm * 128;
  const int tn = xn * 128;

  const int rA0 = lane >> 2;          // row-within-chunk
  const int cA0 = (lane & 3) * 8;     // k offset

  const bf16* Ab = A + (size_t)tm * ED;
  const bf16* Wb = W + (size_t)tn * ED;

  f32x4 acc[4][4] = {};

  for (int k0 = 0; k0 < ED; k0 += 32) {
#pragma unroll
    for (int i = 0; i < 2; ++i) {
      int ci = w * 2 + i;
      int r = ci * 16 + rA0;
      async_load16(Ab + (size_t)r * ED + k0 + cA0, &As[ci * 512]);
      async_load16(Wb + (size_t)r * ED + k0 + cA0, &Bs[ci * 512]);
    }
    __syncthreads();
    bf16x8 af[4], bfr[4];
#pragma unroll
    for (int mt = 0; mt < 4; ++mt)
      af[mt] = *(const bf16x8*)&As[(wm * 64 + mt * 16 + lo) * 32 + hi * 8];
#pragma unroll
    for (int nt = 0; nt < 4; ++nt)
      bfr[nt] = *(const bf16x8*)&Bs[(wn * 64 + nt * 16 + lo) * 32 + hi * 8];
#pragma unroll
    for (int mt = 0; mt < 4; ++mt)
#pragma unroll
      for (int nt = 0; nt < 4; ++nt)
        acc[mt][nt] = __builtin_amdgcn_mfma_f32_16x16x32_bf16(
            af[mt], bfr[nt], acc[mt][nt], 0, 0, 0);
    __syncthreads();
  }

  const int widx = tn >> 12;     // 0=Q 1=K 2=V
  const int f0 = tn & 4095;
  bf16* Ob = widx == 0 ? Qb : (widx == 1 ? Kb : Vtmp);
#pragma unroll
  for (int mt = 0; mt < 4; ++mt) {
#pragma unroll
    for (int nt = 0; nt < 4; ++nt) {
#pragma unroll
      for (int r = 0; r < 4; ++r) {
        int m = tm + wm * 64 + mt * 16 + hi * 4 + r;
        int f = f0 + wn * 64 + nt * 16 + lo;
        int b = m >> 11, s = m & 2047;
        int h = f >> 8, d = f & 255;
        Ob[(((size_t)(b * NH + h) * SEQ) + s) * HD + d] = (bf16)acc[mt][nt][r];
      }
    }
  }
}

// ---------------------------------------------------------------------------
// V transpose: (b,h,s,d) -> (b,h,d,s). 64x64 tiles via padded LDS.
// grid (32 s-tiles, 4 d-tiles, 32 bh), 256 threads.
// ---------------------------------------------------------------------------
__global__ __launch_bounds__(256) void transpose_v(const bf16* __restrict__ src,
                                                   bf16* __restrict__ dst) {
  __shared__ bf16 T[64][72];   // +8 elem pad (16 B) to spread banks
  const int bh = blockIdx.z;
  const int st = blockIdx.x;
  const int dt = blockIdx.y;
  const bf16* S = src + ((size_t)bh * SEQ + st * 64) * HD + dt * 64;
#pragma unroll
  for (int p = 0; p < 2; ++p) {
    int r = p * 32 + (threadIdx.x >> 3), c = (threadIdx.x & 7) * 8;
    *(bf16x8*)&T[r][c] = *(const bf16x8*)(S + (size_t)r * HD + c);
  }
  __syncthreads();
  bf16* D = dst + ((size_t)bh * HD + dt * 64) * SEQ + st * 64;
#pragma unroll
  for (int p = 0; p < 2; ++p) {
    int r = p * 32 + (threadIdx.x >> 3), c = (threadIdx.x & 7) * 8;
    bf16x8 v;
#pragma unroll
    for (int j = 0; j < 8; ++j) v[j] = T[c + j][r];
    *(bf16x8*)(D + (size_t)r * SEQ + c) = v;
  }
}

// ---------------------------------------------------------------------------
// same GEMM, fp32 epilogue to d_out (row-major 4096x4096)
// ---------------------------------------------------------------------------
__global__ __launch_bounds__(256) void gemm_out(
    const bf16* __restrict__ A, const bf16* __restrict__ W,
    float* __restrict__ C) {
  __shared__ bf16 As[128 * 32];
  __shared__ bf16 Bs[128 * 32];
  const int tid = threadIdx.x;
  const int w = tid >> 6, lane = tid & 63;
  const int wm = w >> 1, wn = w & 1;
  const int lo = lane & 15, hi = lane >> 4;
  const int tm = blockIdx.x * 128;
  const int tn = blockIdx.y * 128;

  const int rA0 = lane >> 2;
  const int cA0 = (lane & 3) * 8;

  const bf16* Ab = A + (size_t)tm * ED;
  const bf16* Wb = W + (size_t)tn * ED;

  f32x4 acc[4][4] = {};

  for (int k0 = 0; k0 < ED; k0 += 32) {
#pragma unroll
    for (int i = 0; i < 2; ++i) {
      int ci = w * 2 + i;
      int r = ci * 16 + rA0;
      async_load16(Ab + (size_t)r * ED + k0 + cA0, &As[ci * 512]);
      async_load16(Wb + (size_t)r * ED + k0 + cA0, &Bs[ci * 512]);
    }
    __syncthreads();
    bf16x8 af[4], bfr[4];
#pragma unroll
    for (int mt = 0; mt < 4; ++mt)
      af[mt] = *(const bf16x8*)&As[(wm * 64 + mt * 16 + lo) * 32 + hi * 8];
#pragma unroll
    for (int nt = 0; nt < 4; ++nt)
      bfr[nt] = *(const bf16x8*)&Bs[(wn * 64 + nt * 16 + lo) * 32 + hi * 8];
#pragma unroll
    for (int mt = 0; mt < 4; ++mt)
#pragma unroll
      for (int nt = 0; nt < 4; ++nt)
        acc[mt][nt] = __builtin_amdgcn_mfma_f32_16x16x32_bf16(
            af[mt], bfr[nt], acc[mt][nt], 0, 0, 0);
    __syncthreads();
  }

#pragma unroll
  for (int mt = 0; mt < 4; ++mt)
#pragma unroll
    for (int nt = 0; nt < 4; ++nt)
#pragma unroll
      for (int r = 0; r < 4; ++r) {
        int m = tm + wm * 64 + mt * 16 + hi * 4 + r;
        int n = tn + wn * 64 + nt * 16 + lo;
        C[(size_t)m * ED + n] = acc[mt][nt][r];
      }
}

// ---------------------------------------------------------------------------
// RoPE, vectorized: one thread = 4 interleaved pairs (bf16x8, 16 B).
// grid 4096 x 256: bits = t:1 b:1 h:4 s:11 g:3.
// ---------------------------------------------------------------------------
__global__ void rope_kernel(bf16* __restrict__ Qb, bf16* __restrict__ Kb,
                            const int* __restrict__ pos_ids,
                            const float* __restrict__ emb) {
  int idx = blockIdx.x * 256 + threadIdx.x;
  int g = idx & 7;
  int s = (idx >> 3) & 2047;
  int h = (idx >> 14) & 15;
  int b = (idx >> 18) & 1;
  int t = idx >> 19;
  bf16* T = t ? Kb : Qb;
  int pos = pos_ids[b * SEQ + s];
  const float* e = emb + pos * 64;
  size_t base = (((size_t)(b * NH + h) * SEQ) + s) * HD + g * 8;
  bf16x8 v = *(bf16x8*)(T + base);
  bf16x8 o;
#pragma unroll
  for (int j = 0; j < 4; ++j) {
    int p = g * 4 + j;
    float sn = e[p], cs = e[32 + p];
    float x0 = (float)v[2 * j], x1 = (float)v[2 * j + 1];
    o[2 * j]     = (bf16)(x0 * cs - x1 * sn);
    o[2 * j + 1] = (bf16)(x1 * cs + x0 * sn);
  }
  *(bf16x8*)(T + base) = o;
}

// ---------------------------------------------------------------------------
// Flash attention (causal), qt-paired for load balance.
// Grid: (slot=16, bh=32); block processes qt=slot then qt=31-slot
// -> every block exactly (slot+1)+(32-slot) = 33 K-tile iterations.
// XOR-swizzled LDS (phys chunk = logical chunk ^ (row&7)) keeps all
// b128 reads at free 2-way aliasing. P scratch wave-private.
// ---------------------------------------------------------------------------
__global__ __launch_bounds__(256) void attn_kernel(
    const bf16* __restrict__ Qb, const bf16* __restrict__ Kb,
    const bf16* __restrict__ Vt, bf16* __restrict__ AO) {
  __shared__ bf16 Ks[64 * 256];    // 32 KB
  __shared__ bf16 Vs[256 * 64];    // 32 KB
  __shared__ bf16 Ps[4 * 16 * 64]; // 8 KB, wave-private strips
  const int tid = threadIdx.x;
  const int w = tid >> 6, lane = tid & 63;
  const int lo = lane & 15, hi = lane >> 4;
  const int slot = blockIdx.x;  // 0..15
  const int bh = blockIdx.y;    // 0..31

  const bf16* Qh = Qb + (size_t)bh * SEQ * HD;
  const bf16* Kh = Kb + (size_t)bh * SEQ * HD;
  const bf16* Vh = Vt + (size_t)bh * HD * SEQ;
  const int b = bh >> 4, h = bh & 15;

  for (int half = 0; half < 2; ++half) {
    const int qt = half ? (31 - slot) : slot;

    // Q fragments for this wave's 16-row strip (A-layout), 8 k-steps of 32
    bf16x8 aq[8];
    const int qrow = qt * 64 + w * 16 + lo;
#pragma unroll
    for (int ks = 0; ks < 8; ++ks)
      aq[ks] = *(const bf16x8*)(Qh + (size_t)qrow * HD + ks * 32 + hi * 8);

    f32x4 o[16] = {};
    float mrow[4], lrow[4];
#pragma unroll
    for (int r = 0; r < 4; ++r) { mrow[r] = -3e38f; lrow[r] = 0.f; }

    for (int kt = 0; kt <= qt; ++kt) {
      // stage K tile: 64 rows x 512 B; region ci covers 2 rows.
#pragma unroll
      for (int i = 0; i < 8; ++i) {
        int ci = w * 8 + i;
        int r = ci * 2 + (lane >> 5);
        int cc = (lane & 31) ^ (r & 7);
        async_load16(Kh + ((size_t)(kt * 64 + r)) * HD + cc * 8, &Ks[ci * 512]);
      }
      // stage V tile: 256 d-rows x 128 B; region ci covers 8 rows.
#pragma unroll
      for (int i = 0; i < 8; ++i) {
        int ci = w * 8 + i;
        int d = ci * 8 + (lane >> 3);
        int cc = (lane & 7) ^ (d & 7);
        async_load16(Vh + (size_t)d * SEQ + kt * 64 + cc * 8, &Vs[ci * 512]);
      }
      __syncthreads();

      // S strip: 16 rows x 64 cols
      float sv[4][4];
#pragma unroll
      for (int nt = 0; nt < 4; ++nt) {
        f32x4 sacc = {};
#pragma unroll
        for (int ks = 0; ks < 8; ++ks) {
          int row = nt * 16 + lo;
          bf16x8 bk = *(const bf16x8*)
              &Ks[row * HD + ((((ks << 2) + hi) ^ (row & 7)) << 3)];
          sacc = __builtin_amdgcn_mfma_f32_16x16x32_bf16(aq[ks], bk, sacc, 0, 0, 0);
        }
#pragma unroll
        for (int r = 0; r < 4; ++r) {
          float x = sacc[r] * 0.0625f;
          if (kt == qt) {
            int col = kt * 64 + nt * 16 + lo;
            int row = qt * 64 + w * 16 + hi * 4 + r;
            if (col > row) x = -1e30f;
          }
          sv[nt][r] = x;
        }
      }

      // online softmax (row lives in 16 lanes sharing hi)
      float alpha[4];
#pragma unroll
      for (int r = 0; r < 4; ++r) {
        float mx = fmaxf(fmaxf(sv[0][r], sv[1][r]), fmaxf(sv[2][r], sv[3][r]));
        mx = fmaxf(mx, __shfl_xor(mx, 1));
        mx = fmaxf(mx, __shfl_xor(mx, 2));
        mx = fmaxf(mx, __shfl_xor(mx, 4));
        mx = fmaxf(mx, __shfl_xor(mx, 8));
        float mnew = fmaxf(mrow[r], mx);
        alpha[r] = __expf(mrow[r] - mnew);
        mrow[r] = mnew;
        float sum = 0.f;
#pragma unroll
        for (int nt = 0; nt < 4; ++nt) {
          float p = __expf(sv[nt][r] - mnew);
          sv[nt][r] = p;
          sum += p;
        }
        sum += __shfl_xor(sum, 1);
        sum += __shfl_xor(sum, 2);
        sum += __shfl_xor(sum, 4);
        sum += __shfl_xor(sum, 8);
        lrow[r] = lrow[r] * alpha[r] + sum;
      }

      // rescale O by alpha
#pragma unroll
      for (int nt2 = 0; nt2 < 16; ++nt2)
#pragma unroll
        for (int r = 0; r < 4; ++r) o[nt2][r] *= alpha[r];

      // P: C-layout -> wave-private swizzled LDS strip -> A-layout
#pragma unroll
      for (int nt = 0; nt < 4; ++nt)
#pragma unroll
        for (int r = 0; r < 4; ++r) {
          int prow = hi * 4 + r;
          int chunk = nt * 2 + (lo >> 3);
          Ps[w * 1024 + prow * 64 + (((chunk ^ (prow & 7)) << 3) | (lo & 7))] =
              (bf16)sv[nt][r];
        }
      bf16x8 pa[2];
#pragma unroll
      for (int k2 = 0; k2 < 2; ++k2)
        pa[k2] = *(const bf16x8*)
            &Ps[w * 1024 + lo * 64 + ((((k2 << 2) + hi) ^ (lo & 7)) << 3)];

      // O += P @ V  (16x64 @ 64x256)
#pragma unroll
      for (int nt2 = 0; nt2 < 16; ++nt2) {
#pragma unroll
        for (int k2 = 0; k2 < 2; ++k2) {
          int row = nt2 * 16 + lo;
          bf16x8 bv = *(const bf16x8*)
              &Vs[row * 64 + ((((k2 << 2) + hi) ^ (row & 7)) << 3)];
          o[nt2] = __builtin_amdgcn_mfma_f32_16x16x32_bf16(pa[k2], bv, o[nt2], 0, 0, 0);
        }
      }
      __syncthreads();  // Ks/Vs reads done before next staging
    }

    // epilogue: normalize, write AO as (b, s, h*256+d) bf16
#pragma unroll
    for (int r = 0; r < 4; ++r) {
      float inv = 1.f / lrow[r];
      int srow = qt * 64 + w * 16 + hi * 4 + r;
      size_t base = ((size_t)(b * SEQ + srow)) * ED + h * HD;
#pragma unroll
      for (int nt2 = 0; nt2 < 16; ++nt2)
        AO[base + nt2 * 16 + lo] = (bf16)(o[nt2][r] * inv);
    }
  }
}

// ---------------------------------------------------------------------------
// launch
// ---------------------------------------------------------------------------
extern "C" void kernel_launch(void* const* d_in, const int* in_sizes, int n_in,
                              void* d_out, int out_size, void* d_ws,
                              size_t ws_size, hipStream_t stream) {
  const float* hs  = (const float*)d_in[0];
  const int*   pos = (const int*)d_in[1];
  const float* qw  = (const float*)d_in[2];
  const float* kw  = (const float*)d_in[3];
  const float* vw  = (const float*)d_in[4];
  const float* ow  = (const float*)d_in[5];
  const float* emb = (const float*)d_in[6];
  float* out = (float*)d_out;

  char* ws = (char*)d_ws;
  const size_t MB = 1024 * 1024;
  // [0,32)   Hb  -> AO (attn output) after gemm_qkv consumes Hb
  // [32,128) Wqkv; after gemm_qkv: [32,64) Wo, [64,96) Vt (d,s)
  // [128,160) Qb  [160,192) Kb  [192,224) Vtmp (s,d)
  bf16* Hb   = (bf16*)(ws);
  bf16* AO   = (bf16*)(ws);
  bf16* Wqkv = (bf16*)(ws + 32 * MB);
  bf16* Wo   = (bf16*)(ws + 32 * MB);
  bf16* Vt   = (bf16*)(ws + 64 * MB);
  bf16* Qb   = (bf16*)(ws + 128 * MB);
  bf16* Kb   = (bf16*)(ws + 160 * MB);
  bf16* Vtmp = (bf16*)(ws + 192 * MB);

  const int n = ED * ED;            // 16777216

  // hidden + 3 projection weights in one launch
  cvt4_f32_bf16<<<65536, 256, 0, stream>>>(
      hs, qw, kw, vw, Hb, Wqkv, Wqkv + (size_t)n, Wqkv + 2 * (size_t)n);

  gemm_qkv<<<dim3(32, 96), 256, 0, stream>>>(Hb, Wqkv, Qb, Kb, Vtmp);

  // out_w conversion + V transpose (both into freed Wqkv space)
  cvt_f32_bf16<<<16384, 256, 0, stream>>>(ow, Wo, n);
  transpose_v<<<dim3(32, 4, 32), 256, 0, stream>>>(Vtmp, Vt);

  rope_kernel<<<4096, 256, 0, stream>>>(Qb, Kb, pos, emb);

  attn_kernel<<<dim3(16, 32), 256, 0, stream>>>(Qb, Kb, Vt, AO);

  gemm_out<<<dim3(32, 32), 256, 0, stream>>>(AO, Wo, out);
}